// Round 12
// baseline (116.368 us; speedup 1.0000x reference)
//
#include <hip/hip_runtime.h>
#include <stdint.h>

typedef __attribute__((ext_vector_type(8))) _Float16 half8;
typedef __attribute__((ext_vector_type(2))) __fp16 fp16x2;
typedef __attribute__((ext_vector_type(16))) float floatx16;
typedef __attribute__((ext_vector_type(2))) short s16x2;
typedef unsigned int u32;
typedef unsigned short u16;

#define TPW 4  // tiles (of 32 points) per wave; processed 2 at a time

// f32 pair -> packed f16 (a->low16, b->high16). Builtin returns __fp16-vector.
// NOTE R7: v_cvt_pk_bf16_f32 asm returns garbage on gfx950. NOTE R8: inline-asm
// v_mfma corrupts results (no hazard handling) — intrinsics only.
__device__ __forceinline__ u32 pkf16(float a, float b) {
  union { fp16x2 v; u32 u; } c;
  c.v = __builtin_amdgcn_cvt_pkrtz(a, b);
  return c.u;
}

// relu on packed f16 pair: signed-i16 max with 0. R5/R10-proven.
__device__ __forceinline__ u32 relu_pk(u32 t) {
  union { u32 u; s16x2 v; } c;
  c.u = t;
  s16x2 zz = {0, 0};
  c.v = __builtin_elementwise_max(c.v, zz);  // v_pk_max_i16
  return c.u;
}

__device__ __forceinline__ u16 rtnh(float a) {
  union { _Float16 h; u16 u; } c;
  c.h = (_Float16)a;
  return c.u;
}

__device__ __forceinline__ fp16x2 as_h2(u32 x) {
  union { u32 u; fp16x2 h; } c;
  c.u = x;
  return c.h;
}

// channel<->k-slot permutation (involution): swap bits 2,3 of low nibble.
__device__ __forceinline__ int sigperm(int k) {
  int r = k & 15;
  int s = (r & 3) | ((r & 4) << 1) | ((r & 8) >> 1);
  return (k & ~15) | s;
}

__device__ __forceinline__ half8 packhalf(const floatx16 a, int base, bool relu) {
  union { u32 u[4]; half8 v; } r;
#pragma unroll
  for (int i = 0; i < 4; ++i) {
    u32 t = pkf16(a[base + 2 * i], a[base + 2 * i + 1]);
    r.u[i] = relu ? relu_pk(t) : t;
  }
  return r.v;
}

#define MFMA(A, B, C) __builtin_amdgcn_mfma_f32_32x32x16_f16(A, B, C, 0, 0, 0)

// Frag pool (frag = 64 lanes x 16B):
//  0..1  s0[rt]        2..9  s1[rt*4+ks]    10..17 Wf[rt*4+ks] (= cw0[:,3:18]@sw2[1:,:])
// 18..19 Wv[rt] (views)  20..27 c1   28..35 c2   36..39 c3[ks]
// 40..43 wsig[q]: per-lane sigma-dot weights matching bAq channel order
#define NFRAG 44

__global__ void build_pool(
    const float* __restrict__ w_s0, const float* __restrict__ w_s1,
    const float* __restrict__ w_s2, const float* __restrict__ w_c0,
    const float* __restrict__ w_c1, const float* __restrict__ w_c2,
    const float* __restrict__ w_c3, uint4* __restrict__ pool) {
  const int f = blockIdx.x;
  const int lane = threadIdx.x;      // 0..63
  const int m = lane & 31;
  const int hi = lane >> 5;
  const int kb = hi << 3;

  union { u16 e[8]; uint4 q; } u;
  if (f < 2) {                         // s0: 64x3, K padded to 16
    const int row = f * 32 + m;
#pragma unroll
    for (int j = 0; j < 8; ++j) {
      const int k = kb + j;
      u.e[j] = (k < 3) ? rtnh(w_s0[row * 3 + k]) : (u16)0;
    }
  } else if (f < 10) {                 // s1: 64x64
    const int g = f - 2, rt = g >> 2, ks = g & 3;
    const int row = rt * 32 + m;
#pragma unroll
    for (int j = 0; j < 8; ++j)
      u.e[j] = rtnh(w_s1[row * 64 + sigperm(ks * 16 + kb + j)]);
  } else if (f < 18) {                 // Wf = cw0[:,3:18] @ sw2[1:16,:], 64x64
    const int g = f - 10, rt = g >> 2, ks = g & 3;
    const int row = rt * 32 + m;
#pragma unroll
    for (int j = 0; j < 8; ++j) {
      const int col = sigperm(ks * 16 + kb + j);
      float acc = 0.f;
      for (int g2 = 0; g2 < 15; ++g2)
        acc += w_c0[row * 18 + 3 + g2] * w_s2[(1 + g2) * 64 + col];
      u.e[j] = rtnh(acc);
    }
  } else if (f < 20) {                 // Wv: views, K=16 with slots 0..2 used
    const int rt = f - 18;
    const int row = rt * 32 + m;
#pragma unroll
    for (int j = 0; j < 8; ++j) {
      const int kk = kb + j;
      u16 v = rtnh(w_c0[row * 18 + ((kk < 3) ? kk : 0)]);
      u.e[j] = (kk < 3) ? v : (u16)0;
    }
  } else if (f < 28) {                 // c1: 64x64
    const int g = f - 20, rt = g >> 2, ks = g & 3;
    const int row = rt * 32 + m;
#pragma unroll
    for (int j = 0; j < 8; ++j)
      u.e[j] = rtnh(w_c1[row * 64 + sigperm(ks * 16 + kb + j)]);
  } else if (f < 36) {                 // c2: 64x64
    const int g = f - 28, rt = g >> 2, ks = g & 3;
    const int row = rt * 32 + m;
#pragma unroll
    for (int j = 0; j < 8; ++j)
      u.e[j] = rtnh(w_c2[row * 64 + sigperm(ks * 16 + kb + j)]);
  } else if (f < 40) {                 // c3: 3x64 (rows 3..31 zero)
    const int ks = f - 36;
    const int row = (m < 3) ? m : 0;
#pragma unroll
    for (int j = 0; j < 8; ++j) {
      u16 v = rtnh(w_c3[row * 64 + sigperm(ks * 16 + kb + j)]);
      u.e[j] = (m < 3) ? v : (u16)0;
    }
  } else {                             // wsig[q]: sw2 row 0 in bAq lane order
    const int q = f - 40;
#pragma unroll
    for (int j = 0; j < 8; ++j) {
      const int c = 16 * q + (j & 3) + 8 * (j >> 2) + 4 * hi;
      u.e[j] = rtnh(w_s2[c]);          // row 0 of sw2 (16x64)
    }
  }
  pool[f * 64 + lane] = u.q;
}

// live set ~150 unified regs (arch + MFMA acc). (256,2) gives the allocator
// 256/wave — no spill possible; true residency was ~2 waves/SIMD anyway.
// (512,7) spilled catastrophically in R6 (650 us).
__global__ __launch_bounds__(256, 2) void nerf_fused(
    const float* __restrict__ x, const uint4* __restrict__ pool,
    float* __restrict__ out, int npts) {
  __shared__ __align__(16) u16 wl[NFRAG * 512];  // 45056 B

  {
    uint4* lp = (uint4*)wl;
    for (int i = threadIdx.x; i < NFRAG * 64; i += 256) lp[i] = pool[i];
  }
  __syncthreads();

  const int lane = threadIdx.x & 63;
  const int wid = threadIdx.x >> 6;
  const int m = lane & 31;
  const int hi = lane >> 5;

#define LD(F) (*(const half8*)(wl + (F) * 512 + lane * 8))

  // hoist sigma-dot weights (loop-invariant): 16 u32
  u32 wsig[16];
#pragma unroll
  for (int q = 0; q < 4; ++q) {
    const u32* p = (const u32*)(wl + (40 + q) * 512 + lane * 8);
#pragma unroll
    for (int i = 0; i < 4; ++i) wsig[q * 4 + i] = p[i];
  }

  const int ntiles = npts >> 5;
  const int wgid = blockIdx.x * 4 + wid;
  const floatx16 z = (floatx16)0.0f;

  for (int t = 0; t < TPW; t += 2) {
    const int tileA = wgid * TPW + t;
    if (tileA >= ntiles) break;
    const int ptA = (tileA << 5) | m;
    const int ptB = ptA + 32;

    const float2* xpA = (const float2*)(x + (size_t)ptA * 6);
    const float2 a0 = xpA[0], a1 = xpA[1], a2 = xpA[2];
    const float2* xpB = (const float2*)(x + (size_t)ptB * 6);
    const float2 c0_ = xpB[0], c1_ = xpB[1], c2_ = xpB[2];

    union { u32 u[4]; half8 v; } bxA, bvA, bxB, bvB;
    bxA.u[0] = hi ? 0u : pkf16(a0.x, a0.y);
    bxA.u[1] = hi ? 0u : pkf16(a1.x, 0.0f);
    bxA.u[2] = 0u; bxA.u[3] = 0u;
    bvA.u[0] = hi ? 0u : pkf16(a1.y, a2.x);
    bvA.u[1] = hi ? 0u : pkf16(a2.y, 0.0f);
    bvA.u[2] = 0u; bvA.u[3] = 0u;
    bxB.u[0] = hi ? 0u : pkf16(c0_.x, c0_.y);
    bxB.u[1] = hi ? 0u : pkf16(c1_.x, 0.0f);
    bxB.u[2] = 0u; bxB.u[3] = 0u;
    bvB.u[0] = hi ? 0u : pkf16(c1_.y, c2_.x);
    bvB.u[1] = hi ? 0u : pkf16(c2_.y, 0.0f);
    bvB.u[2] = 0u; bvB.u[3] = 0u;

    floatx16 hA0, hA1, hB0, hB1;
    half8 w;

    // sigma L0 (K=3 padded)
    w = LD(0); hA0 = MFMA(w, bxA.v, z); hB0 = MFMA(w, bxB.v, z);
    w = LD(1); hA1 = MFMA(w, bxA.v, z); hB1 = MFMA(w, bxB.v, z);
    half8 bA0 = packhalf(hA0, 0, true), bA1 = packhalf(hA0, 8, true);
    half8 bA2 = packhalf(hA1, 0, true), bA3 = packhalf(hA1, 8, true);
    half8 bB0 = packhalf(hB0, 0, true), bB1 = packhalf(hB0, 8, true);
    half8 bB2 = packhalf(hB1, 0, true), bB3 = packhalf(hB1, 8, true);

    // sigma L1 (64->64) -> h2
    w = LD(2); hA0 = MFMA(w, bA0, z);   hB0 = MFMA(w, bB0, z);
    w = LD(6); hA1 = MFMA(w, bA0, z);   hB1 = MFMA(w, bB0, z);
    w = LD(3); hA0 = MFMA(w, bA1, hA0); hB0 = MFMA(w, bB1, hB0);
    w = LD(7); hA1 = MFMA(w, bA1, hA1); hB1 = MFMA(w, bB1, hB1);
    w = LD(4); hA0 = MFMA(w, bA2, hA0); hB0 = MFMA(w, bB2, hB0);
    w = LD(8); hA1 = MFMA(w, bA2, hA1); hB1 = MFMA(w, bB2, hB1);
    w = LD(5); hA0 = MFMA(w, bA3, hA0); hB0 = MFMA(w, bB3, hB0);
    w = LD(9); hA1 = MFMA(w, bA3, hA1); hB1 = MFMA(w, bB3, hB1);
    bA0 = packhalf(hA0, 0, true); bA1 = packhalf(hA0, 8, true);
    bA2 = packhalf(hA1, 0, true); bA3 = packhalf(hA1, 8, true);
    bB0 = packhalf(hB0, 0, true); bB1 = packhalf(hB0, 8, true);
    bB2 = packhalf(hB1, 0, true); bB3 = packhalf(hB1, 8, true);

    // sigma = sw2[0,:] . h2 — v_dot2 chain, off the MFMA critical path
    float sA = 0.f, sB = 0.f;
    {
      union { half8 v; u32 u[4]; } fA[4] = {{bA0}, {bA1}, {bA2}, {bA3}};
      union { half8 v; u32 u[4]; } fB[4] = {{bB0}, {bB1}, {bB2}, {bB3}};
#pragma unroll
      for (int q = 0; q < 4; ++q)
#pragma unroll
        for (int i = 0; i < 4; ++i) {
          sA = __builtin_amdgcn_fdot2(as_h2(fA[q].u[i]), as_h2(wsig[q * 4 + i]), sA, false);
          sB = __builtin_amdgcn_fdot2(as_h2(fB[q].u[i]), as_h2(wsig[q * 4 + i]), sB, false);
        }
    }
    sA += __shfl_xor(sA, 32, 64);  // combine the two half-wave channel sets
    sB += __shfl_xor(sB, 32, 64);

    // color L0' = relu(Wv.views + Wf.h2)  [s2+c0 fused: no relu between them]
    w = LD(18); hA0 = MFMA(w, bvA.v, z); hB0 = MFMA(w, bvB.v, z);
    w = LD(19); hA1 = MFMA(w, bvA.v, z); hB1 = MFMA(w, bvB.v, z);
    w = LD(10); hA0 = MFMA(w, bA0, hA0); hB0 = MFMA(w, bB0, hB0);
    w = LD(14); hA1 = MFMA(w, bA0, hA1); hB1 = MFMA(w, bB0, hB1);
    w = LD(11); hA0 = MFMA(w, bA1, hA0); hB0 = MFMA(w, bB1, hB0);
    w = LD(15); hA1 = MFMA(w, bA1, hA1); hB1 = MFMA(w, bB1, hB1);
    w = LD(12); hA0 = MFMA(w, bA2, hA0); hB0 = MFMA(w, bB2, hB0);
    w = LD(16); hA1 = MFMA(w, bA2, hA1); hB1 = MFMA(w, bB2, hB1);
    w = LD(13); hA0 = MFMA(w, bA3, hA0); hB0 = MFMA(w, bB3, hB0);
    w = LD(17); hA1 = MFMA(w, bA3, hA1); hB1 = MFMA(w, bB3, hB1);
    bA0 = packhalf(hA0, 0, true); bA1 = packhalf(hA0, 8, true);
    bA2 = packhalf(hA1, 0, true); bA3 = packhalf(hA1, 8, true);
    bB0 = packhalf(hB0, 0, true); bB1 = packhalf(hB0, 8, true);
    bB2 = packhalf(hB1, 0, true); bB3 = packhalf(hB1, 8, true);

    // color L1
    w = LD(20); hA0 = MFMA(w, bA0, z);   hB0 = MFMA(w, bB0, z);
    w = LD(24); hA1 = MFMA(w, bA0, z);   hB1 = MFMA(w, bB0, z);
    w = LD(21); hA0 = MFMA(w, bA1, hA0); hB0 = MFMA(w, bB1, hB0);
    w = LD(25); hA1 = MFMA(w, bA1, hA1); hB1 = MFMA(w, bB1, hB1);
    w = LD(22); hA0 = MFMA(w, bA2, hA0); hB0 = MFMA(w, bB2, hB0);
    w = LD(26); hA1 = MFMA(w, bA2, hA1); hB1 = MFMA(w, bB2, hB1);
    w = LD(23); hA0 = MFMA(w, bA3, hA0); hB0 = MFMA(w, bB3, hB0);
    w = LD(27); hA1 = MFMA(w, bA3, hA1); hB1 = MFMA(w, bB3, hB1);
    bA0 = packhalf(hA0, 0, true); bA1 = packhalf(hA0, 8, true);
    bA2 = packhalf(hA1, 0, true); bA3 = packhalf(hA1, 8, true);
    bB0 = packhalf(hB0, 0, true); bB1 = packhalf(hB0, 8, true);
    bB2 = packhalf(hB1, 0, true); bB3 = packhalf(hB1, 8, true);

    // color L2
    w = LD(28); hA0 = MFMA(w, bA0, z);   hB0 = MFMA(w, bB0, z);
    w = LD(32); hA1 = MFMA(w, bA0, z);   hB1 = MFMA(w, bB0, z);
    w = LD(29); hA0 = MFMA(w, bA1, hA0); hB0 = MFMA(w, bB1, hB0);
    w = LD(33); hA1 = MFMA(w, bA1, hA1); hB1 = MFMA(w, bB1, hB1);
    w = LD(30); hA0 = MFMA(w, bA2, hA0); hB0 = MFMA(w, bB2, hB0);
    w = LD(34); hA1 = MFMA(w, bA2, hA1); hB1 = MFMA(w, bB2, hB1);
    w = LD(31); hA0 = MFMA(w, bA3, hA0); hB0 = MFMA(w, bB3, hB0);
    w = LD(35); hA1 = MFMA(w, bA3, hA1); hB1 = MFMA(w, bB3, hB1);
    bA0 = packhalf(hA0, 0, true); bA1 = packhalf(hA0, 8, true);
    bA2 = packhalf(hA1, 0, true); bA3 = packhalf(hA1, 8, true);
    bB0 = packhalf(hB0, 0, true); bB1 = packhalf(hB0, 8, true);
    bB2 = packhalf(hB1, 0, true); bB3 = packhalf(hB1, 8, true);

    // color L3 (64->3, NO relu)
    floatx16 hcA, hcB;
    w = LD(36); hcA = MFMA(w, bA0, z);   hcB = MFMA(w, bB0, z);
    w = LD(37); hcA = MFMA(w, bA1, hcA); hcB = MFMA(w, bB1, hcB);
    w = LD(38); hcA = MFMA(w, bA2, hcA); hcB = MFMA(w, bB2, hcB);
    w = LD(39); hcA = MFMA(w, bA3, hcA); hcB = MFMA(w, bB3, hcB);

    if (lane < 32) {
      float4 oA, oB;
      oA.x = hcA[0]; oA.y = hcA[1]; oA.z = hcA[2]; oA.w = sA;
      oB.x = hcB[0]; oB.y = hcB[1]; oB.z = hcB[2]; oB.w = sB;
      *(float4*)(out + (size_t)ptA * 4) = oA;
      *(float4*)(out + (size_t)ptB * 4) = oB;
    }
  }
#undef LD
}

extern "C" void kernel_launch(void* const* d_in, const int* in_sizes, int n_in,
                              void* d_out, int out_size, void* d_ws, size_t ws_size,
                              hipStream_t stream) {
  const float* x = (const float*)d_in[0];
  const float* sw0 = (const float*)d_in[1];
  const float* sw1 = (const float*)d_in[2];
  const float* sw2 = (const float*)d_in[3];
  const float* cw0 = (const float*)d_in[4];
  const float* cw1 = (const float*)d_in[5];
  const float* cw2 = (const float*)d_in[6];
  const float* cw3 = (const float*)d_in[7];
  float* out = (float*)d_out;
  uint4* pool = (uint4*)d_ws;  // 45056 B used

  const int npts = in_sizes[0] / 6;         // 1048576
  const int ntiles = npts >> 5;             // 32768
  const int blocks = (ntiles + 4 * TPW - 1) / (4 * TPW);  // 2048

  build_pool<<<NFRAG, 64, 0, stream>>>(sw0, sw1, sw2, cw0, cw1, cw2, cw3, pool);
  nerf_fused<<<blocks, 256, 0, stream>>>(x, pool, out, npts);
}